// Round 3
// baseline (99.829 us; speedup 1.0000x reference)
//
#include <hip/hip_runtime.h>
#include <math.h>

// out[b, p(i,j)] = sigmoid( relu( (x_i|x_j)@W1+b1 @ W2 + b2 ) @ W3 + b3 )
// Net is LINEAR until ReLU -> fold once:
//   AB[0:4] = W1[0:4]@W2, AB[4:8] = W1[4:8]@W2 (4x100 each), c = b1@W2+b2
// Per-node: U[b,n,h] = x[b,n]·AB[0:4][:,h] + c[h],  V[b,n,h] = x[b,n]·AB[4:8][:,h]
//   out = sigmoid( sum_h W3[h]*relu(U[i,h]+V[j,h]) + b3 )
//
// 3 kernels: fold (once) -> compute_uv (materialize U,V transposed [b][h][n]
// in d_ws, 6.6 MB) -> pairnet_pair (32x32 tiles, LDS, 4x2 register blocking).

namespace {
constexpr int B_    = 64;
constexpr int N_    = 128;
constexpr int H_    = 100;
constexpr int TILE  = 32;
constexpr int NT    = N_ / TILE;            // 4
constexpr int NTP   = NT * (NT + 1) / 2;    // 10
constexpr int PAIRS = N_ * (N_ - 1) / 2;    // 8128
constexpr int FOLD_AB = 0;                  // [8][100]
constexpr int FOLD_C  = 800;                // [100]
constexpr int FOLD_W3 = 900;                // [100]
constexpr int FOLD_B3 = 1000;               // scalar
constexpr int UVSZ    = B_ * H_ * N_;       // 819200 floats per tensor
}

__device__ float g_fold[1001];

__global__ __launch_bounds__(256)
void fold_weights(const float* __restrict__ W1, const float* __restrict__ b1,
                  const float* __restrict__ W2, const float* __restrict__ b2,
                  const float* __restrict__ W3, const float* __restrict__ b3)
{
    const int idx = blockIdx.x * 256 + threadIdx.x;   // 0..1023
    if (idx < 800) {
        const int r = idx / H_;           // W1 row 0..7
        const int h = idx - r * H_;
        const float* w1r = W1 + r * H_;
        float s = 0.f;
        #pragma unroll 5
        for (int j = 0; j < H_; ++j) s = fmaf(w1r[j], W2[j * H_ + h], s);
        g_fold[FOLD_AB + idx] = s;
    } else if (idx < 900) {
        const int h = idx - 800;
        float s = b2[h];
        #pragma unroll 5
        for (int j = 0; j < H_; ++j) s = fmaf(b1[j], W2[j * H_ + h], s);
        g_fold[FOLD_C + h] = s;
    } else if (idx < 1000) {
        g_fold[FOLD_W3 + (idx - 900)] = W3[idx - 900];
    } else if (idx == 1000) {
        g_fold[FOLD_B3] = b3[0];
    }
}

// U,V stored transposed: U[b][h][n] so the pair kernel stages tiles with
// straight coalesced float4 copies (no on-the-fly transpose).
__global__ __launch_bounds__(256)
void compute_uv(const float* __restrict__ x,
                float* __restrict__ Uw, float* __restrict__ Vw)
{
    const int t   = threadIdx.x;
    const int blk = blockIdx.x;               // 64 * 50
    const int b   = blk / 50;
    const int h   = (blk - b * 50) * 2 + (t >> 7);   // wave-uniform
    const int n   = t & 127;
    const float4 xv = ((const float4*)x)[b * N_ + n];
    const float u = g_fold[FOLD_C + h]
        + xv.x * g_fold[FOLD_AB + 0 * H_ + h]
        + xv.y * g_fold[FOLD_AB + 1 * H_ + h]
        + xv.z * g_fold[FOLD_AB + 2 * H_ + h]
        + xv.w * g_fold[FOLD_AB + 3 * H_ + h];
    const float v =
          xv.x * g_fold[FOLD_AB + 4 * H_ + h]
        + xv.y * g_fold[FOLD_AB + 5 * H_ + h]
        + xv.z * g_fold[FOLD_AB + 6 * H_ + h]
        + xv.w * g_fold[FOLD_AB + 7 * H_ + h];
    const int o = (b * H_ + h) * N_ + n;      // coalesced
    Uw[o] = u;
    Vw[o] = v;
}

__global__ __launch_bounds__(128)
void pairnet_pair(const float* __restrict__ Uw, const float* __restrict__ Vw,
                  float* __restrict__ out)
{
    __shared__ float U_s[H_][TILE];           // 12.8 KB
    __shared__ float V_s[H_][TILE];           // 12.8 KB

    const int t   = threadIdx.x;              // 0..127 (2 waves)
    const int blk = blockIdx.x;
    const int b   = blk / NTP;
    int rem = blk - b * NTP;
    int ti = 0;
    while (rem >= NT - ti) { rem -= NT - ti; ++ti; }
    const int tj = ti + rem;                  // ti <= tj
    const int i0 = ti * TILE, j0 = tj * TILE;

    // ---- stage tiles: pure coalesced float4 copies (8 float4 per h-row)
    const float4* U4 = (const float4*)Uw;
    const float4* V4 = (const float4*)Vw;
    for (int idx = t; idx < 800; idx += 128) {
        const int h = idx >> 3, q = idx & 7;
        *(float4*)&U_s[h][4 * q] = U4[(b * H_ + h) * 32 + 8 * ti + q];
    }
    for (int idx = t; idx < 800; idx += 128) {
        const int h = idx >> 3, q = idx & 7;
        *(float4*)&V_s[h][4 * q] = V4[(b * H_ + h) * 32 + 8 * tj + q];
    }
    __syncthreads();

    // ---- 4 rows x 2 cols per thread: u=b128 (4 distinct addrs/wave, banks
    // disjoint), v=b64 (16 distinct addrs spanning all 32 banks) -> conflict-free
    const int iq = t >> 4;                    // 0..7  -> rows 4*iq..4*iq+3
    const int jq = t & 15;                    // 0..15 -> cols 2*jq, 2*jq+1
    float acc[4][2] = {};
    #pragma unroll 2
    for (int h = 0; h < H_; ++h) {
        const float  w = g_fold[FOLD_W3 + h];         // uniform -> s_load
        const float4 u = *(const float4*)&U_s[h][4 * iq];
        const float2 v = *(const float2*)&V_s[h][2 * jq];
        const float us[4] = {u.x, u.y, u.z, u.w};
        const float vs[2] = {v.x, v.y};
        #pragma unroll
        for (int r = 0; r < 4; ++r)
            #pragma unroll
            for (int c = 0; c < 2; ++c)
                acc[r][c] = fmaf(w, fmaxf(us[r] + vs[c], 0.f), acc[r][c]);
    }

    const float b3v = g_fold[FOLD_B3];
    float* outb = out + b * PAIRS;
    #pragma unroll
    for (int r = 0; r < 4; ++r) {
        #pragma unroll
        for (int c = 0; c < 2; ++c) {
            const int gi = i0 + 4 * iq + r;
            const int gj = j0 + 2 * jq + c;
            if (gi < gj) {                    // masks lower half of diagonal tiles
                const int p = (gi * (2 * N_ - gi - 1)) / 2 + (gj - gi - 1);
                outb[p] = 1.f / (1.f + __expf(-(acc[r][c] + b3v)));
            }
        }
    }
}

extern "C" void kernel_launch(void* const* d_in, const int* in_sizes, int n_in,
                              void* d_out, int out_size, void* d_ws, size_t ws_size,
                              hipStream_t stream) {
    const float* x  = (const float*)d_in[0];
    // d_in[1] = in_hitnr: unused by the reference computation
    const float* W1 = (const float*)d_in[2];
    const float* b1 = (const float*)d_in[3];
    const float* W2 = (const float*)d_in[4];
    const float* b2 = (const float*)d_in[5];
    const float* W3 = (const float*)d_in[6];
    const float* b3 = (const float*)d_in[7];
    float* out = (float*)d_out;

    float* Uw = (float*)d_ws;                 // 3.28 MB
    float* Vw = Uw + UVSZ;                    // 3.28 MB (ws_size is ~256 MB)

    fold_weights<<<dim3(4),        dim3(256), 0, stream>>>(W1, b1, W2, b2, W3, b3);
    compute_uv  <<<dim3(B_ * 50),  dim3(256), 0, stream>>>(x, Uw, Vw);
    pairnet_pair<<<dim3(B_ * NTP), dim3(128), 0, stream>>>(Uw, Vw, out);
}

// Round 4
// 85.616 us; speedup vs baseline: 1.1660x; 1.1660x over previous
//
#include <hip/hip_runtime.h>
#include <math.h>

// out[b, p(i,j)] = sigmoid( relu( (x_i|x_j)@W1+b1 @ W2 + b2 ) @ W3 + b3 )
// Net is LINEAR until the ReLU -> fold once:
//   A[k][h] = (W1[0:4]@W2)[k][h], Bm[k][h] = (W1[4:8]@W2)[k][h], c = b1@W2+b2
//   U[b,n,h] = x[b,n]·A[:,h] + c[h],  V[b,n,h] = x[b,n]·Bm[:,h]
//   out = sigmoid( sum_h W3[h]*relu(U[i,h]+V[j,h]) + b3 )
//
// 2 kernels only (per-iteration floor is the harness's 256MB ws re-poison fill;
// extra dependent launches cost ~5-10us each -> consolidate):
//   K1 fold_weights -> g_fold2 global, h-major [100][12] rows {A0..3,B0..3,c,pad3}
//   K2 pairnet: 640 blocks (64 b x 10 tile-pairs, 32x32), 256 thr. Stages fold
//      table into LDS (one float4 burst), builds U/V tiles in LDS from x,
//      2x2-register-blocked pair loop with b128 LDS reads (conflict-free).

namespace {
constexpr int B_    = 64;
constexpr int N_    = 128;
constexpr int H_    = 100;
constexpr int TILE  = 32;
constexpr int NT    = N_ / TILE;            // 4
constexpr int NTP   = NT * (NT + 1) / 2;    // 10
constexpr int PAIRS = N_ * (N_ - 1) / 2;    // 8128
constexpr int FROW  = 12;                   // floats per h-row (48B, 16B-aligned)
constexpr int FW3   = H_ * FROW;            // w3[100] at 1200
constexpr int FB3   = FW3 + H_;             // b3 at 1300
constexpr int FTOT  = 1304;                 // padded to /4
}

__device__ __align__(16) float g_fold2[FTOT];

__global__ __launch_bounds__(128)
void fold_weights(const float* __restrict__ W1, const float* __restrict__ b1,
                  const float* __restrict__ W2, const float* __restrict__ b2,
                  const float* __restrict__ W3, const float* __restrict__ b3)
{
    const int idx = blockIdx.x * 128 + threadIdx.x;   // 8 blocks -> 0..1023
    if (idx < 800) {
        const int k = idx / H_;            // W1 row 0..7 (0..3 = A, 4..7 = B)
        const int h = idx - k * H_;        // consecutive idx -> consecutive h: W2 coalesced
        const float* w1r = W1 + k * H_;
        float s = 0.f;
        #pragma unroll 5
        for (int j = 0; j < H_; ++j) s = fmaf(w1r[j], W2[j * H_ + h], s);
        g_fold2[h * FROW + k] = s;
    } else if (idx < 900) {
        const int h = idx - 800;
        float s = b2[h];
        #pragma unroll 5
        for (int j = 0; j < H_; ++j) s = fmaf(b1[j], W2[j * H_ + h], s);
        g_fold2[h * FROW + 8] = s;
    } else if (idx < 1000) {
        g_fold2[FW3 + (idx - 900)] = W3[idx - 900];
    } else if (idx == 1000) {
        g_fold2[FB3] = b3[0];
    }
}

__global__ __launch_bounds__(256)
void pairnet(const float* __restrict__ x, float* __restrict__ out)
{
    // fold table + interleaved U/V tiles: element (r,h) at [h>>1][r][h&1]
    __shared__ __align__(16) float fold_s[FTOT];        // 5.2 KB
    __shared__ __align__(16) float U_s[50 * TILE * 2];  // 12.8 KB
    __shared__ __align__(16) float V_s[50 * TILE * 2];  // 12.8 KB

    const int t   = threadIdx.x;            // 0..255
    const int blk = blockIdx.x;
    const int b   = blk / NTP;
    int rem = blk - b * NTP;
    int ti = 0;
    while (rem >= NT - ti) { rem -= NT - ti; ++ti; }
    const int tj = ti + rem;                // ti <= tj
    const int i0 = ti * TILE, j0 = tj * TILE;

    // ---- stage fold table: 326 float4, one coalesced burst (+20 stragglers)
    {
        const float4* gf4 = (const float4*)g_fold2;
        float4* fs4 = (float4*)fold_s;
        fs4[t & 255] = gf4[t & 255];        // t<256 covers 0..255
        if (t < FTOT / 4 - 256) fs4[256 + t] = gf4[256 + t];
    }
    // per-thread x rows (r = t&31 for ALL its UV items below)
    const int r = t & 31;
    const float4 xi = ((const float4*)x)[b * N_ + i0 + r];
    const float4 xj = ((const float4*)x)[b * N_ + j0 + r];
    __syncthreads();

    // ---- build U/V tiles: 1600 (h2,r) items, each computes h0=2*h2 and h1
    for (int k = 0; k < 7; ++k) {
        const int idx = t + k * 256;
        if (idx < 1600) {
            const int h2 = idx >> 5;               // uniform per 32 lanes
            // idx & 31 == t & 31 == r
            const float* row0 = &fold_s[(2 * h2) * FROW];
            const float* row1 = &fold_s[(2 * h2 + 1) * FROW];
            const float4 a0 = *(const float4*)(row0);
            const float4 b0 = *(const float4*)(row0 + 4);
            const float4 a1 = *(const float4*)(row1);
            const float4 b1v = *(const float4*)(row1 + 4);
            float2 u, v;
            u.x = row0[8] + xi.x*a0.x + xi.y*a0.y + xi.z*a0.z + xi.w*a0.w;
            u.y = row1[8] + xi.x*a1.x + xi.y*a1.y + xi.z*a1.z + xi.w*a1.w;
            v.x =           xj.x*b0.x + xj.y*b0.y + xj.z*b0.z + xj.w*b0.w;
            v.y =           xj.x*b1v.x + xj.y*b1v.y + xj.z*b1v.z + xj.w*b1v.w;
            *(float2*)&U_s[h2 * 64 + r * 2] = u;
            *(float2*)&V_s[h2 * 64 + r * 2] = v;
        }
    }
    __syncthreads();

    // ---- 2x2 pairs per thread; per h2: u=b128, v=b128, w=b64 (all conflict-free)
    const int iq = t >> 4;                  // 0..15 -> rows 2iq,2iq+1
    const int jq = t & 15;                  // 0..15 -> cols 2jq,2jq+1
    const int ia = 2 * iq, ja = 2 * jq;
    float a00 = 0.f, a01 = 0.f, a10 = 0.f, a11 = 0.f;
    #pragma unroll 2
    for (int h2 = 0; h2 < 50; ++h2) {
        const float2 w = *(const float2*)&fold_s[FW3 + 2 * h2];
        // u = {U[ia][h0],U[ia][h1],U[ia+1][h0],U[ia+1][h1]}
        const float4 u = *(const float4*)&U_s[h2 * 64 + ia * 2];
        const float4 v = *(const float4*)&V_s[h2 * 64 + ja * 2];
        a00 = fmaf(w.x, fmaxf(u.x + v.x, 0.f), fmaf(w.y, fmaxf(u.y + v.y, 0.f), a00));
        a01 = fmaf(w.x, fmaxf(u.x + v.z, 0.f), fmaf(w.y, fmaxf(u.y + v.w, 0.f), a01));
        a10 = fmaf(w.x, fmaxf(u.z + v.x, 0.f), fmaf(w.y, fmaxf(u.w + v.y, 0.f), a10));
        a11 = fmaf(w.x, fmaxf(u.z + v.z, 0.f), fmaf(w.y, fmaxf(u.w + v.w, 0.f), a11));
    }

    const float b3v = fold_s[FB3];
    float* outb = out + b * PAIRS;
    const float accs[2][2] = {{a00, a01}, {a10, a11}};
    #pragma unroll
    for (int da = 0; da < 2; ++da) {
        #pragma unroll
        for (int dc = 0; dc < 2; ++dc) {
            const int gi = i0 + ia + da;
            const int gj = j0 + ja + dc;
            if (gi < gj) {                  // masks lower half of diagonal tiles
                const int p = (gi * (2 * N_ - gi - 1)) / 2 + (gj - gi - 1);
                outb[p] = 1.f / (1.f + __expf(-(accs[da][dc] + b3v)));
            }
        }
    }
}

extern "C" void kernel_launch(void* const* d_in, const int* in_sizes, int n_in,
                              void* d_out, int out_size, void* d_ws, size_t ws_size,
                              hipStream_t stream) {
    const float* x  = (const float*)d_in[0];
    // d_in[1] = in_hitnr: unused by the reference computation
    const float* W1 = (const float*)d_in[2];
    const float* b1 = (const float*)d_in[3];
    const float* W2 = (const float*)d_in[4];
    const float* b2 = (const float*)d_in[5];
    const float* W3 = (const float*)d_in[6];
    const float* b3 = (const float*)d_in[7];
    float* out = (float*)d_out;

    fold_weights<<<dim3(8),        dim3(128), 0, stream>>>(W1, b1, W2, b2, W3, b3);
    pairnet     <<<dim3(B_ * NTP), dim3(256), 0, stream>>>(x, out);
}

// Round 5
// 85.123 us; speedup vs baseline: 1.1728x; 1.0058x over previous
//
#include <hip/hip_runtime.h>
#include <math.h>

// out[b, p(i,j)] = sigmoid( relu( (x_i|x_j)@W1+b1 @ W2 + b2 ) @ W3 + b3 )
// Net is LINEAR until the ReLU -> fold:
//   fold[h] = {A[0:4][h]=W1[0:4]@W2, B[0:4][h]=W1[4:8]@W2, c[h]=b1@W2+b2}
//   U[n,h] = x[n]·A[:,h] + c[h],  V[n,h] = x[n]·B[:,h]
//   out    = sigmoid( sum_h W3[h]*relu(U[i,h]+V[j,h]) + b3 )
//
// SINGLE kernel (R1-R3 showed each extra graph node costs ~5-8us vs the
// harness's fixed ~41us ws-refill floor): every block re-folds the weights
// from an LDS-staged copy of W1/W2 -- cheap because:
//   - W2 staged with a FLAT float4 copy (same [j][h] layout the fold reads;
//     fold read W2s[j*100+h] has h-consecutive lanes -> conflict-free b32)
//   - W1 transposed to W1T[j][12] rows {k0..7, b1j} -> one b128 broadcast/j
//   - 200 threads x 5 accumulators (k-quad + c) -> ~1us/block, 3 blocks/CU
// LDS: fold_s 5.2KB + union(stage 44.8KB | U/V 25.6KB) = 50KB -> 3 blocks/CU,
// all 640 blocks in one residency round.

namespace {
constexpr int B_    = 64;
constexpr int N_    = 128;
constexpr int H_    = 100;
constexpr int TILE  = 32;
constexpr int NT    = N_ / TILE;            // 4
constexpr int NTP   = NT * (NT + 1) / 2;    // 10
constexpr int PAIRS = N_ * (N_ - 1) / 2;    // 8128
constexpr int FROW  = 12;                   // floats per fold h-row {A0..3,B0..3,c,pad3}
constexpr int FW3   = H_ * FROW;            // w3[100] at 1200
constexpr int FB3   = FW3 + H_;             // b3 at 1300
constexpr int FTOT  = 1304;
constexpr int SCR   = 11200;                // floats: max(W2 10000 + W1T 1200, U/V 6400)
}

__global__ __launch_bounds__(256)
void pairnet_one(const float* __restrict__ x,
                 const float* __restrict__ W1, const float* __restrict__ b1,
                 const float* __restrict__ W2, const float* __restrict__ b2,
                 const float* __restrict__ W3, const float* __restrict__ b3,
                 float* __restrict__ out)
{
    __shared__ __align__(16) float fold_s[FTOT];
    __shared__ __align__(16) float scratch[SCR];
    float* const W2s = scratch;              // [100][100] flat copy of W2
    float* const W1T = scratch + 10000;      // [100][12] rows {W1[0..7][j], b1[j]}
    float* const U_s = scratch;              // after fold: [50][32][2] interleaved
    float* const V_s = scratch + 3200;

    const int t   = threadIdx.x;             // 0..255
    const int blk = blockIdx.x;
    const int b   = blk / NTP;
    int rem = blk - b * NTP;
    int ti = 0;
    while (rem >= NT - ti) { rem -= NT - ti; ++ti; }
    const int tj = ti + rem;                 // ti <= tj
    const int i0 = ti * TILE, j0 = tj * TILE;

    // per-thread x rows, loaded early (independent of LDS phases)
    const int r = t & 31;
    const float4 xi = ((const float4*)x)[b * N_ + i0 + r];
    const float4 xj = ((const float4*)x)[b * N_ + j0 + r];

    // ---- stage: W2 flat float4 copy (coalesced, conflict-free)
    {
        const float4* W2g = (const float4*)W2;
        float4* W2s4 = (float4*)W2s;
        #pragma unroll
        for (int k = 0; k < 10; ++k) {
            const int idx = t + k * 256;
            if (idx < 2500) W2s4[idx] = W2g[idx];
        }
        // W1 -> W1T[j][k], b1 -> W1T[j][8]
        for (int idx = t; idx < 800; idx += 256) {
            const int k = idx / 100, j = idx - k * 100;
            W1T[j * FROW + k] = W1[idx];
        }
        if (t < 100) W1T[t * FROW + 8] = b1[t];
        if (t < 100) fold_s[FW3 + t] = W3[t];
        if (t == 0)  fold_s[FB3] = b3[0];
    }
    __syncthreads();

    // ---- fold: 200 active threads; half 0: h=t, k=0..3 + c; half 1: h=t-100, k=4..7
    if (t < 200) {
        const int half = t / 100;            // wave-uniform except wave 1
        const int h    = t - half * 100;
        float a0 = 0.f, a1 = 0.f, a2 = 0.f, a3 = 0.f;
        float ac = (half == 0) ? b2[h] : 0.f;
        #pragma unroll 4
        for (int j = 0; j < H_; ++j) {
            const float  w2 = W2s[j * H_ + h];                     // lanes: h-consecutive
            const float4 w1 = *(const float4*)&W1T[j * FROW + 4 * half]; // broadcast
            a0 = fmaf(w2, w1.x, a0);
            a1 = fmaf(w2, w1.y, a1);
            a2 = fmaf(w2, w1.z, a2);
            a3 = fmaf(w2, w1.w, a3);
            if (half == 0) ac = fmaf(w2, W1T[j * FROW + 8], ac);   // broadcast
        }
        float* row = &fold_s[h * FROW + 4 * half];
        row[0] = a0; row[1] = a1; row[2] = a2; row[3] = a3;
        if (half == 0) fold_s[h * FROW + 8] = ac;
    }
    __syncthreads();   // fold_s ready; stage region may now be overwritten by U/V

    // ---- build U/V tiles, interleaved: element (r,h) at [h>>1][r][h&1]
    #pragma unroll
    for (int k = 0; k < 7; ++k) {
        const int idx = t + k * 256;
        if (idx < 1600) {
            const int h2 = idx >> 5;                 // idx&31 == r
            const float* row0 = &fold_s[(2 * h2) * FROW];
            const float* row1 = &fold_s[(2 * h2 + 1) * FROW];
            const float4 a0  = *(const float4*)(row0);
            const float4 b0  = *(const float4*)(row0 + 4);
            const float4 a1  = *(const float4*)(row1);
            const float4 b1v = *(const float4*)(row1 + 4);
            float2 u, v;
            u.x = row0[8] + xi.x*a0.x  + xi.y*a0.y  + xi.z*a0.z  + xi.w*a0.w;
            u.y = row1[8] + xi.x*a1.x  + xi.y*a1.y  + xi.z*a1.z  + xi.w*a1.w;
            v.x =           xj.x*b0.x  + xj.y*b0.y  + xj.z*b0.z  + xj.w*b0.w;
            v.y =           xj.x*b1v.x + xj.y*b1v.y + xj.z*b1v.z + xj.w*b1v.w;
            *(float2*)&U_s[h2 * 64 + r * 2] = u;
            *(float2*)&V_s[h2 * 64 + r * 2] = v;
        }
    }
    __syncthreads();

    // ---- 2x2 pairs/thread; per h2: w=b64 bcast, u=b128 (4 addrs, disjoint
    // bank-quads), v=b128 (2-way = free) -> conflict-free
    const int iq = t >> 4;                   // 0..15 -> rows 2iq,2iq+1
    const int jq = t & 15;                   // 0..15 -> cols 2jq,2jq+1
    const int ia = 2 * iq, ja = 2 * jq;
    float a00 = 0.f, a01 = 0.f, a10 = 0.f, a11 = 0.f;
    #pragma unroll 2
    for (int h2 = 0; h2 < 50; ++h2) {
        const float2 w = *(const float2*)&fold_s[FW3 + 2 * h2];
        const float4 u = *(const float4*)&U_s[h2 * 64 + ia * 2];
        const float4 v = *(const float4*)&V_s[h2 * 64 + ja * 2];
        a00 = fmaf(w.x, fmaxf(u.x + v.x, 0.f), fmaf(w.y, fmaxf(u.y + v.y, 0.f), a00));
        a01 = fmaf(w.x, fmaxf(u.x + v.z, 0.f), fmaf(w.y, fmaxf(u.y + v.w, 0.f), a01));
        a10 = fmaf(w.x, fmaxf(u.z + v.x, 0.f), fmaf(w.y, fmaxf(u.w + v.y, 0.f), a10));
        a11 = fmaf(w.x, fmaxf(u.z + v.z, 0.f), fmaf(w.y, fmaxf(u.w + v.w, 0.f), a11));
    }

    const float b3v = fold_s[FB3];
    float* outb = out + b * PAIRS;
    const float accs[2][2] = {{a00, a01}, {a10, a11}};
    #pragma unroll
    for (int da = 0; da < 2; ++da) {
        #pragma unroll
        for (int dc = 0; dc < 2; ++dc) {
            const int gi = i0 + ia + da;
            const int gj = j0 + ja + dc;
            if (gi < gj) {                   // masks lower half of diagonal tiles
                const int p = (gi * (2 * N_ - gi - 1)) / 2 + (gj - gi - 1);
                outb[p] = 1.f / (1.f + __expf(-(accs[da][dc] + b3v)));
            }
        }
    }
}

extern "C" void kernel_launch(void* const* d_in, const int* in_sizes, int n_in,
                              void* d_out, int out_size, void* d_ws, size_t ws_size,
                              hipStream_t stream) {
    const float* x  = (const float*)d_in[0];
    // d_in[1] = in_hitnr: unused by the reference computation
    const float* W1 = (const float*)d_in[2];
    const float* b1 = (const float*)d_in[3];
    const float* W2 = (const float*)d_in[4];
    const float* b2 = (const float*)d_in[5];
    const float* W3 = (const float*)d_in[6];
    const float* b3 = (const float*)d_in[7];
    float* out = (float*)d_out;

    pairnet_one<<<dim3(B_ * NTP), dim3(256), 0, stream>>>(
        x, W1, b1, W2, b2, W3, b3, out);
}